// Round 16
// baseline (520.095 us; speedup 1.0000x reference)
//
#include <hip/hip_runtime.h>
#include <hip/hip_bf16.h>

#define NCLS 345
#define CPAD 384
#define DIM  512
#define BCAP 256

typedef float f32x4 __attribute__((ext_vector_type(4)));
typedef short s16x8 __attribute__((ext_vector_type(8)));
typedef short s16x4 __attribute__((ext_vector_type(4)));
typedef unsigned long long u64;

__device__ __forceinline__ short f2bf(float f) {
  union { float f; unsigned u; } v; v.f = f;
  unsigned r = v.u + 0x7fffu + ((v.u >> 16) & 1u);   // RNE
  return (short)(r >> 16);
}

// ---- Stage 1 ----
__global__ __launch_bounds__(256) void scan_classes(
    const float* __restrict__ ent, const int* __restrict__ y_hat,
    u64* __restrict__ bucket, int* __restrict__ cnt, int N)
{
  int i = blockIdx.x * 256 + threadIdx.x;
  if (i >= N) return;
  int c = y_hat[i];
  unsigned eb = __float_as_uint(ent[i]);
  u64 key = ((u64)eb << 32) | (unsigned)i;
  int p = atomicAdd(&cnt[c], 1);
  if (p < BCAP) bucket[(size_t)c * BCAP + p] = key;
}

// ---- Stage 2: select + normalized-row sum -> fragment-packed W ----
__global__ __launch_bounds__(512) void select_accum(
    const float* __restrict__ supports, const u64* __restrict__ bucket,
    const int* __restrict__ cnt, const int* __restrict__ fKp,
    short* __restrict__ Wp)
{
  const int c = blockIdx.x;
  const int tid = threadIdx.x;
  const int lane = tid & 63, w = tid >> 6;
  __shared__ u64   s_key[BCAP];
  __shared__ int   s_selidx[BCAP];
  __shared__ int   s_nsel;
  __shared__ float s_part[8][DIM];
  __shared__ float s_red[8];
  if (tid == 0) s_nsel = 0;
  const int S = (c < NCLS) ? min(cnt[c], BCAP) : 0;
  const int K = fKp[0];
  for (int e = tid; e < S; e += 512) s_key[e] = bucket[(size_t)c * BCAP + e];
  __syncthreads();
  for (int e = tid; e < S; e += 512) {
    u64 ke = s_key[e];
    int r = 0;
    for (int j = 0; j < S; ++j) r += (s_key[j] < ke) ? 1 : 0;
    if (r < K) { int p = atomicAdd(&s_nsel, 1); s_selidx[p] = (int)(unsigned)(ke & 0xffffffffull); }
  }
  __syncthreads();
  const int nsel = s_nsel;
  f32x4 p0 = {0.f,0.f,0.f,0.f}, p1 = {0.f,0.f,0.f,0.f};
  for (int e0 = w; e0 < nsel; e0 += 16) {
    const int e1 = e0 + 8;
    const bool h1 = (e1 < nsel);
    const f32x4* r0 = (const f32x4*)(supports + (size_t)s_selidx[e0] * DIM);
    f32x4 a0 = r0[lane], a1 = r0[lane + 64];
    f32x4 b0 = {0.f,0.f,0.f,0.f}, b1 = {0.f,0.f,0.f,0.f};
    if (h1) {
      const f32x4* r1 = (const f32x4*)(supports + (size_t)s_selidx[e1] * DIM);
      b0 = r1[lane]; b1 = r1[lane + 64];
    }
    float s0 = 0.f, s1 = 0.f;
#pragma unroll
    for (int j = 0; j < 4; ++j) {
      s0 = fmaf(a0[j], a0[j], s0); s0 = fmaf(a1[j], a1[j], s0);
      s1 = fmaf(b0[j], b0[j], s1); s1 = fmaf(b1[j], b1[j], s1);
    }
#pragma unroll
    for (int off = 32; off; off >>= 1) { s0 += __shfl_xor(s0, off); s1 += __shfl_xor(s1, off); }
    float c0 = 1.f / fmaxf(sqrtf(s0), 1e-12f);
    float c1 = 1.f / fmaxf(sqrtf(s1), 1e-12f);
#pragma unroll
    for (int j = 0; j < 4; ++j) { p0[j] = fmaf(a0[j], c0, p0[j]); p1[j] = fmaf(a1[j], c0, p1[j]); }
    if (h1) {
#pragma unroll
      for (int j = 0; j < 4; ++j) { p0[j] = fmaf(b0[j], c1, p0[j]); p1[j] = fmaf(b1[j], c1, p1[j]); }
    }
  }
  *(f32x4*)&s_part[w][lane * 4]       = p0;
  *(f32x4*)&s_part[w][256 + lane * 4] = p1;
  __syncthreads();
  float acc = 0.f;
#pragma unroll
  for (int ww = 0; ww < 8; ++ww) acc += s_part[ww][tid];
  float sq = acc * acc;
#pragma unroll
  for (int off = 32; off; off >>= 1) sq += __shfl_xor(sq, off);
  if (lane == 0) s_red[w] = sq;
  __syncthreads();
  float tot = 0.f;
#pragma unroll
  for (int ww = 0; ww < 8; ++ww) tot += s_red[ww];
  float sc = 1.f / fmaxf(sqrtf(tot), 1e-12f);
  {
    const int k = tid;
    const int kt = k >> 5, fq = (k >> 3) & 3, j = k & 7;
    const int ct = c >> 4, fr = c & 15;
    const size_t pos = (size_t)(kt * 24 + ct) * 512 + fq * 128 + fr * 8 + j;
    Wp[pos] = f2bf(acc * sc);
  }
}

// ---- Kernel B: R13 + per-wave K-phase rotation (t2 = (t+2w)&15) ----
__global__ __launch_bounds__(512, 4) void gemm_zw(
    const float* __restrict__ z, const short* __restrict__ Wp,
    float* __restrict__ out)
{
  __shared__ __align__(16) char lds[65536];
  const int tid  = threadIdx.x;
  const int lane = tid & 63;
  const int w    = tid >> 6;
  const int fr   = lane & 15, fq = lane >> 4;
  const int Mbase = blockIdx.x * 64;

#pragma unroll
  for (int i = 0; i < 8; ++i) {
    const int row = i * 8 + w;
    const char* src = (const char*)(z + (size_t)(Mbase + row) * DIM);
    f32x4 v0 = *(const f32x4*)(src + lane * 16);
    f32x4 v1 = *(const f32x4*)(src + 1024 + lane * 16);
    s16x4 b0, b1;
#pragma unroll
    for (int j = 0; j < 4; ++j) { b0[j] = f2bf(v0[j]); b1[j] = f2bf(v1[j]); }
    const unsigned so = ((unsigned)(lane >> 1) ^ ((unsigned)row & 7)) * 16 + (lane & 1) * 8;
    *(s16x4*)(lds + row * 1024 + so)       = b0;
    *(s16x4*)(lds + row * 1024 + 512 + so) = b1;
  }
  __syncthreads();

  const char* pb = (const char*)Wp + (size_t)w * 3 * 1024 + (size_t)lane * 16;
  const int ph = 2 * w;                          // per-wave K-phase offset

  f32x4 acc[4][3];
#pragma unroll
  for (int mt = 0; mt < 4; ++mt)
#pragma unroll
    for (int nt = 0; nt < 3; ++nt) acc[mt][nt] = f32x4{0.f, 0.f, 0.f, 0.f};

  s16x8 Bbuf[4][3];
#pragma unroll
  for (int s = 0; s < 3; ++s)
#pragma unroll
    for (int nt = 0; nt < 3; ++nt)
      Bbuf[s][nt] = *(const s16x8*)(pb + (size_t)((s + ph) & 15) * 24576 + nt * 1024);

#pragma unroll
  for (int t = 0; t < 16; ++t) {
    const int t2 = (t + ph) & 15;                // this wave's K-step
    if (t + 3 < 16) {
#pragma unroll
      for (int nt = 0; nt < 3; ++nt)
        Bbuf[(t + 3) & 3][nt] = *(const s16x8*)(pb + (size_t)((t + 3 + ph) & 15) * 24576 + nt * 1024);
    }
    s16x8 af[4];
#pragma unroll
    for (int mt = 0; mt < 4; ++mt) {
      const int row = mt * 16 + fr;
      const unsigned slot = ((unsigned)(t2 * 4) + fq) ^ ((unsigned)row & 7);
      af[mt] = *(const s16x8*)(lds + row * 1024 + slot * 16);
    }
    __builtin_amdgcn_s_setprio(1);
#pragma unroll
    for (int nt = 0; nt < 3; ++nt)
#pragma unroll
      for (int mt = 0; mt < 4; ++mt)
        acc[mt][nt] = __builtin_amdgcn_mfma_f32_16x16x32_bf16(Bbuf[t & 3][nt], af[mt], acc[mt][nt], 0, 0, 0);
    __builtin_amdgcn_s_setprio(0);
  }

#pragma unroll
  for (int h = 0; h < 2; ++h) {
    __syncthreads();
#pragma unroll
    for (int ml = 0; ml < 2; ++ml) {
      const int mt = h * 2 + ml;
      const int rl = ml * 16 + fr;
#pragma unroll
      for (int nt = 0; nt < 3; ++nt) {
        const int colb = w * 48 + nt * 16 + fq * 4;
#pragma unroll
        for (int j = 0; j < 4; ++j) {
          const int col = colb + j;
          if (col < NCLS)
            *(float*)(lds + (((size_t)rl * NCLS + col) << 2)) = acc[mt][nt][j];
        }
      }
    }
    __syncthreads();
    char* dst = (char*)(out + (size_t)(Mbase + h * 32) * NCLS);
    for (int c = tid; c < 2760; c += 512) {
      f32x4 v = *(const f32x4*)(lds + c * 16);
      __builtin_nontemporal_store(v, (f32x4*)(dst + c * 16));
    }
  }
}

// ---- Ablation probe: gemm K-loop with the B-PATH DELETED (x6 reps) ----
// A-stage + A ds_reads + MFMA identical to gemm_zw; B frags are lane
// constants. Writes acc token to ws. Pre-committed read:
//   dur 70-120us, high MfmaUtil  -> B-path was the limiter (H1)
//   dur >=280us                  -> A-LDS/MFMA path is the limiter (H2/H3)
__global__ __launch_bounds__(512, 4) void probe_noB(
    const float* __restrict__ z, float* __restrict__ ws)
{
  __shared__ __align__(16) char lds[65536];
  const int tid  = threadIdx.x;
  const int lane = tid & 63;
  const int w    = tid >> 6;
  const int fr   = lane & 15, fq = lane >> 4;
  const int Mbase = (blockIdx.x & 1023) * 64;

#pragma unroll
  for (int i = 0; i < 8; ++i) {
    const int row = i * 8 + w;
    const char* src = (const char*)(z + (size_t)(Mbase + row) * DIM);
    f32x4 v0 = *(const f32x4*)(src + lane * 16);
    f32x4 v1 = *(const f32x4*)(src + 1024 + lane * 16);
    s16x4 b0, b1;
#pragma unroll
    for (int j = 0; j < 4; ++j) { b0[j] = f2bf(v0[j]); b1[j] = f2bf(v1[j]); }
    const unsigned so = ((unsigned)(lane >> 1) ^ ((unsigned)row & 7)) * 16 + (lane & 1) * 8;
    *(s16x4*)(lds + row * 1024 + so)       = b0;
    *(s16x4*)(lds + row * 1024 + 512 + so) = b1;
  }
  __syncthreads();

  s16x8 bf[3];
#pragma unroll
  for (int nt = 0; nt < 3; ++nt)
#pragma unroll
    for (int j = 0; j < 8; ++j) bf[nt][j] = (short)(lane * 7 + nt * 9 + j);

  f32x4 acc[4][3];
#pragma unroll
  for (int mt = 0; mt < 4; ++mt)
#pragma unroll
    for (int nt = 0; nt < 3; ++nt) acc[mt][nt] = f32x4{0.f, 0.f, 0.f, 0.f};

#pragma unroll 1
  for (int rep = 0; rep < 6; ++rep) {
#pragma unroll
    for (int t = 0; t < 16; ++t) {
      s16x8 af[4];
#pragma unroll
      for (int mt = 0; mt < 4; ++mt) {
        const int row = mt * 16 + fr;
        const unsigned slot = ((unsigned)(t * 4) + fq) ^ ((unsigned)row & 7);
        af[mt] = *(const s16x8*)(lds + row * 1024 + slot * 16);
      }
      __builtin_amdgcn_s_setprio(1);
#pragma unroll
      for (int nt = 0; nt < 3; ++nt)
#pragma unroll
        for (int mt = 0; mt < 4; ++mt)
          acc[mt][nt] = __builtin_amdgcn_mfma_f32_16x16x32_bf16(bf[nt], af[mt], acc[mt][nt], 0, 0, 0);
      __builtin_amdgcn_s_setprio(0);
    }
  }
  f32x4 tok = acc[0][0];
#pragma unroll
  for (int mt = 0; mt < 4; ++mt)
#pragma unroll
    for (int nt = 0; nt < 3; ++nt) tok += acc[mt][nt];
  *(f32x4*)(ws + ((size_t)blockIdx.x * 512 + tid) * 4) = tok;
}

extern "C" void kernel_launch(void* const* d_in, const int* in_sizes, int n_in,
                              void* d_out, int out_size, void* d_ws, size_t ws_size,
                              hipStream_t stream) {
  const float* z        = (const float*)d_in[0];
  const float* supports = (const float*)d_in[1];
  const float* ent      = (const float*)d_in[2];
  const int*   y_hat    = (const int*)d_in[3];
  const int*   fK       = (const int*)d_in[4];
  float* out = (float*)d_out;
  short* Wp  = (short*)d_ws;
  const int N = in_sizes[2];
  const int M = in_sizes[0] / DIM;

  const size_t offC = (size_t)CPAD * DIM * 2;
  const size_t offB = offC + 2048;
  int* cnt    = (int*)((char*)d_ws + offC);
  u64* bucket = (u64*)((char*)d_ws + offB);
  hipMemsetAsync(cnt, 0, CPAD * sizeof(int), stream);
  scan_classes<<<dim3((N + 255) / 256), dim3(256), 0, stream>>>(ent, y_hat, bucket, cnt, N);
  select_accum<<<dim3(CPAD), dim3(512), 0, stream>>>(supports, bucket, cnt, fK, Wp);
  gemm_zw<<<dim3(M / 64), dim3(512), 0, stream>>>(z, Wp, out);
  // ablation probe (writes only to ws scratch at +16MB)
  float* wsp = (float*)((char*)d_ws + (16u << 20));
  probe_noB<<<dim3(M / 64), dim3(512), 0, stream>>>(z, wsp);
}

// Round 17
// 88.262 us; speedup vs baseline: 5.8926x; 5.8926x over previous
//
#include <hip/hip_runtime.h>
#include <hip/hip_bf16.h>

#define NCLS 345
#define CPAD 384
#define DIM  512
#define BCAP 256

typedef float f32x4  __attribute__((ext_vector_type(4)));
typedef float f32x16 __attribute__((ext_vector_type(16)));
typedef short s16x8  __attribute__((ext_vector_type(8)));
typedef short s16x4  __attribute__((ext_vector_type(4)));
typedef unsigned long long u64;

__device__ __forceinline__ short f2bf(float f) {
  union { float f; unsigned u; } v; v.f = f;
  unsigned r = v.u + 0x7fffu + ((v.u >> 16) & 1u);   // RNE
  return (short)(r >> 16);
}

// ---- Stage 1: one pass over N, bucket (ent_bits<<32)|idx per class ----
__global__ __launch_bounds__(256) void scan_classes(
    const float* __restrict__ ent, const int* __restrict__ y_hat,
    u64* __restrict__ bucket, int* __restrict__ cnt, int N)
{
  int i = blockIdx.x * 256 + threadIdx.x;
  if (i >= N) return;
  int c = y_hat[i];
  unsigned eb = __float_as_uint(ent[i]);
  u64 key = ((u64)eb << 32) | (unsigned)i;
  int p = atomicAdd(&cnt[c], 1);
  if (p < BCAP) bucket[(size_t)c * BCAP + p] = key;
}

// ---- Stage 2: select + normalized-row sum -> W packed as 32x32x16 A-slot frags ----
// Frag(kt 0..31, ct 0..11) of 1024B; slot s (=lane) holds
// W[col = ct*32 + (s&31)][k = kt*16 + (s>>5)*8 + j], j = 0..7.
__global__ __launch_bounds__(512) void select_accum(
    const float* __restrict__ supports, const u64* __restrict__ bucket,
    const int* __restrict__ cnt, const int* __restrict__ fKp,
    short* __restrict__ Wp)
{
  const int c = blockIdx.x;
  const int tid = threadIdx.x;
  const int lane = tid & 63, w = tid >> 6;
  __shared__ u64   s_key[BCAP];
  __shared__ int   s_selidx[BCAP];
  __shared__ int   s_nsel;
  __shared__ float s_part[8][DIM];
  __shared__ float s_red[8];
  if (tid == 0) s_nsel = 0;
  const int S = (c < NCLS) ? min(cnt[c], BCAP) : 0;
  const int K = fKp[0];
  for (int e = tid; e < S; e += 512) s_key[e] = bucket[(size_t)c * BCAP + e];
  __syncthreads();
  for (int e = tid; e < S; e += 512) {
    u64 ke = s_key[e];
    int r = 0;
    for (int j = 0; j < S; ++j) r += (s_key[j] < ke) ? 1 : 0;
    if (r < K) { int p = atomicAdd(&s_nsel, 1); s_selidx[p] = (int)(unsigned)(ke & 0xffffffffull); }
  }
  __syncthreads();
  const int nsel = s_nsel;
  f32x4 p0 = {0.f,0.f,0.f,0.f}, p1 = {0.f,0.f,0.f,0.f};
  for (int e0 = w; e0 < nsel; e0 += 16) {
    const int e1 = e0 + 8;
    const bool h1 = (e1 < nsel);
    const f32x4* r0 = (const f32x4*)(supports + (size_t)s_selidx[e0] * DIM);
    f32x4 a0 = r0[lane], a1 = r0[lane + 64];
    f32x4 b0 = {0.f,0.f,0.f,0.f}, b1 = {0.f,0.f,0.f,0.f};
    if (h1) {
      const f32x4* r1 = (const f32x4*)(supports + (size_t)s_selidx[e1] * DIM);
      b0 = r1[lane]; b1 = r1[lane + 64];
    }
    float s0 = 0.f, s1 = 0.f;
#pragma unroll
    for (int j = 0; j < 4; ++j) {
      s0 = fmaf(a0[j], a0[j], s0); s0 = fmaf(a1[j], a1[j], s0);
      s1 = fmaf(b0[j], b0[j], s1); s1 = fmaf(b1[j], b1[j], s1);
    }
#pragma unroll
    for (int off = 32; off; off >>= 1) { s0 += __shfl_xor(s0, off); s1 += __shfl_xor(s1, off); }
    float c0 = 1.f / fmaxf(sqrtf(s0), 1e-12f);
    float c1 = 1.f / fmaxf(sqrtf(s1), 1e-12f);
#pragma unroll
    for (int j = 0; j < 4; ++j) { p0[j] = fmaf(a0[j], c0, p0[j]); p1[j] = fmaf(a1[j], c0, p1[j]); }
    if (h1) {
#pragma unroll
      for (int j = 0; j < 4; ++j) { p0[j] = fmaf(b0[j], c1, p0[j]); p1[j] = fmaf(b1[j], c1, p1[j]); }
    }
  }
  *(f32x4*)&s_part[w][lane * 4]       = p0;
  *(f32x4*)&s_part[w][256 + lane * 4] = p1;
  __syncthreads();
  float acc = 0.f;
#pragma unroll
  for (int ww = 0; ww < 8; ++ww) acc += s_part[ww][tid];
  float sq = acc * acc;
#pragma unroll
  for (int off = 32; off; off >>= 1) sq += __shfl_xor(sq, off);
  if (lane == 0) s_red[w] = sq;
  __syncthreads();
  float tot = 0.f;
#pragma unroll
  for (int ww = 0; ww < 8; ++ww) tot += s_red[ww];
  float sc = 1.f / fmaxf(sqrtf(tot), 1e-12f);
  {
    const int k = tid;                                  // 0..511
    const int ct = c >> 5;                              // col-tile 0..11
    const int lp = (c & 31) + 32 * ((k >> 3) & 1);      // slot in frag
    const int kt = k >> 4, j = k & 7;
    const size_t pos = (size_t)(kt * 12 + ct) * 512 + lp * 8 + j;
    Wp[pos] = f2bf(acc * sc);
  }
}

// ---- Kernel B: out[M,345] = z[M,512] @ W  via mfma 32x32x16 ----
// A in LDS FRAGMENT-LINEAR (frag = band x kt, slot = lane, slot^=(kt&7) quad
// permute -> conflict-free b128 reads; half the ds_read count of 16x16 path).
// B: 32x32-A-slot packed Wp, 1KB contiguous wave-loads from L2.
// 8 waves = 2 row-bands x 4 col-groups (96 cols = 3 tiles). Zero-barrier loop.
// Epilogue: m74 C-mapping -> LDS C-blob -> flat NT stores.
__global__ __launch_bounds__(512, 4) void gemm_zw(
    const float* __restrict__ z, const short* __restrict__ Wp,
    float* __restrict__ out)
{
  __shared__ __align__(16) char lds[65536];      // A frags: 2 bands x 32 kt x 1KB
  const int tid  = threadIdx.x;
  const int lane = tid & 63;
  const int w    = tid >> 6;
  const int band = w >> 2;                       // 0..1 (32 z-rows)
  const int cg   = w & 3;                        // 0..3 (96 classes = 3 tiles)
  const int Mbase = blockIdx.x * 64;

  // ---- stage A: wave w stages rows {i*8+w}; frag-linear scatter, kt-XOR ----
#pragma unroll
  for (int i = 0; i < 8; ++i) {
    const int row = i * 8 + w;
    const char* src = (const char*)(z + (size_t)(Mbase + row) * DIM);
    f32x4 v0 = *(const f32x4*)(src + lane * 16);          // k = 4*lane ..+3
    f32x4 v1 = *(const f32x4*)(src + 1024 + lane * 16);   // k = 256+4*lane
    s16x4 b0, b1;
#pragma unroll
    for (int j = 0; j < 4; ++j) { b0[j] = f2bf(v0[j]); b1[j] = f2bf(v1[j]); }
    const int rt = row >> 5, r5 = row & 31;
    const int kt0 = lane >> 2;                    // 0..15  (v1: +16, same &7)
    const int kh  = (lane >> 1) & 1;
    const int j0  = (lane & 1) * 4;
    const int slot = (r5 + 32 * kh) ^ (kt0 & 7);
    char* base = lds + (size_t)rt * 32768 + slot * 16 + j0 * 2;
    *(s16x4*)(base + kt0 * 1024)        = b0;
    *(s16x4*)(base + (16 + kt0) * 1024) = b1;
  }
  __syncthreads();                               // only pre-epilogue barrier

  // B pointers: frag(kt, ct=cg*3+nt) at (kt*12+ct)*1024 + lane*16
  const char* pb = (const char*)Wp + ((size_t)cg * 3) * 1024 + (size_t)lane * 16;
  const char* pa = lds + (size_t)band * 32768;

  f32x16 acc[3];
#pragma unroll
  for (int nt = 0; nt < 3; ++nt)
#pragma unroll
    for (int e = 0; e < 16; ++e) acc[nt][e] = 0.f;

#pragma unroll
  for (int t = 0; t < 16; ++t) {
    s16x8 bf[2][3];
#pragma unroll
    for (int kk = 0; kk < 2; ++kk) {
      const int kt = 2 * t + kk;
#pragma unroll
      for (int nt = 0; nt < 3; ++nt)
        bf[kk][nt] = *(const s16x8*)(pb + (size_t)(kt * 12 + nt) * 1024);
    }
    s16x8 af[2];
#pragma unroll
    for (int kk = 0; kk < 2; ++kk) {
      const int kt = 2 * t + kk;
      af[kk] = *(const s16x8*)(pa + kt * 1024 + ((lane ^ (kt & 7)) * 16));
    }
    __builtin_amdgcn_s_setprio(1);
#pragma unroll
    for (int kk = 0; kk < 2; ++kk)
#pragma unroll
      for (int nt = 0; nt < 3; ++nt)
        acc[nt] = __builtin_amdgcn_mfma_f32_32x32x16_bf16(bf[kk][nt], af[kk], acc[nt], 0, 0, 0);
    __builtin_amdgcn_s_setprio(0);
  }

  // ---- epilogue: two 32-row halves; m74 mapping: D row(class) =
  // (reg&3)+8*(reg>>2)+4*(lane>>5), D col(z-row) = lane&31 ----
  const int rl = lane & 31;
  const int half = lane >> 5;
#pragma unroll
  for (int h = 0; h < 2; ++h) {
    __syncthreads();                   // h=0: A reads done; h=1: copy done
    if (band == h) {
#pragma unroll
      for (int nt = 0; nt < 3; ++nt) {
#pragma unroll
        for (int q = 0; q < 4; ++q) {
          const int col = cg * 96 + nt * 32 + q * 8 + 4 * half;
          f32x4 v = { acc[nt][q*4], acc[nt][q*4+1], acc[nt][q*4+2], acc[nt][q*4+3] };
          if (col + 3 < NCLS) {
            *(f32x4*)(lds + (((size_t)rl * NCLS + col) << 2)) = v;
          } else if (col < NCLS) {
#pragma unroll
            for (int j = 0; j < 4; ++j)
              if (col + j < NCLS)
                *(float*)(lds + (((size_t)rl * NCLS + col + j) << 2)) = v[j];
          }
        }
      }
    }
    __syncthreads();
    // flat coalesced nontemporal copy: 32*345*4 = 44160 B = 2760 x 16B
    char* dst = (char*)(out + (size_t)(Mbase + h * 32) * NCLS);
    for (int c = tid; c < 2760; c += 512) {
      f32x4 v = *(const f32x4*)(lds + c * 16);
      __builtin_nontemporal_store(v, (f32x4*)(dst + c * 16));
    }
  }
}

extern "C" void kernel_launch(void* const* d_in, const int* in_sizes, int n_in,
                              void* d_out, int out_size, void* d_ws, size_t ws_size,
                              hipStream_t stream) {
  const float* z        = (const float*)d_in[0];
  const float* supports = (const float*)d_in[1];
  const float* ent      = (const float*)d_in[2];
  const int*   y_hat    = (const int*)d_in[3];
  const int*   fK       = (const int*)d_in[4];
  float* out = (float*)d_out;
  short* Wp  = (short*)d_ws;           // fragment-packed W, 384 KB
  const int N = in_sizes[2];
  const int M = in_sizes[0] / DIM;

  const size_t offC = (size_t)CPAD * DIM * 2;          // 393216
  const size_t offB = offC + 2048;
  int* cnt    = (int*)((char*)d_ws + offC);
  u64* bucket = (u64*)((char*)d_ws + offB);
  hipMemsetAsync(cnt, 0, CPAD * sizeof(int), stream);
  scan_classes<<<dim3((N + 255) / 256), dim3(256), 0, stream>>>(ent, y_hat, bucket, cnt, N);
  select_accum<<<dim3(CPAD), dim3(512), 0, stream>>>(supports, bucket, cnt, fK, Wp);
  gemm_zw<<<dim3(M / 64), dim3(512), 0, stream>>>(z, Wp, out);
}

// Round 18
// 78.124 us; speedup vs baseline: 6.6573x; 1.1298x over previous
//
#include <hip/hip_runtime.h>
#include <hip/hip_bf16.h>

#define NCLS 345
#define CPAD 384
#define DIM  512
#define BCAP 256

typedef float f32x4 __attribute__((ext_vector_type(4)));
typedef short s16x8 __attribute__((ext_vector_type(8)));
typedef short s16x4 __attribute__((ext_vector_type(4)));
typedef unsigned long long u64;

__device__ __forceinline__ short f2bf(float f) {
  union { float f; unsigned u; } v; v.f = f;
  unsigned r = v.u + 0x7fffu + ((v.u >> 16) & 1u);   // RNE
  return (short)(r >> 16);
}

// ---- Stage 1: one pass over N, bucket (ent_bits<<32)|idx per class ----
__global__ __launch_bounds__(256) void scan_classes(
    const float* __restrict__ ent, const int* __restrict__ y_hat,
    u64* __restrict__ bucket, int* __restrict__ cnt, int N)
{
  int i = blockIdx.x * 256 + threadIdx.x;
  if (i >= N) return;
  int c = y_hat[i];
  unsigned eb = __float_as_uint(ent[i]);
  u64 key = ((u64)eb << 32) | (unsigned)i;
  int p = atomicAdd(&cnt[c], 1);
  if (p < BCAP) bucket[(size_t)c * BCAP + p] = key;
}

// ---- Stage 2: per-class select + normalized-row sum, emit FRAGMENT-PACKED W ----
// Packed: frag(kt 0..15, ct 0..23) of 1024B; lane = fq*16+fr holds
// W[col = ct*16+fr][k = kt*32+fq*8+j], j=0..7.
__global__ __launch_bounds__(512) void select_accum(
    const float* __restrict__ supports, const u64* __restrict__ bucket,
    const int* __restrict__ cnt, const int* __restrict__ fKp,
    short* __restrict__ Wp)
{
  const int c = blockIdx.x;
  const int tid = threadIdx.x;
  const int lane = tid & 63, w = tid >> 6;
  __shared__ u64   s_key[BCAP];
  __shared__ int   s_selidx[BCAP];
  __shared__ int   s_nsel;
  __shared__ float s_part[8][DIM];
  __shared__ float s_red[8];
  if (tid == 0) s_nsel = 0;
  const int S = (c < NCLS) ? min(cnt[c], BCAP) : 0;
  const int K = fKp[0];
  for (int e = tid; e < S; e += 512) s_key[e] = bucket[(size_t)c * BCAP + e];
  __syncthreads();
  for (int e = tid; e < S; e += 512) {
    u64 ke = s_key[e];
    int r = 0;
    for (int j = 0; j < S; ++j) r += (s_key[j] < ke) ? 1 : 0;
    if (r < K) { int p = atomicAdd(&s_nsel, 1); s_selidx[p] = (int)(unsigned)(ke & 0xffffffffull); }
  }
  __syncthreads();
  const int nsel = s_nsel;
  f32x4 p0 = {0.f,0.f,0.f,0.f}, p1 = {0.f,0.f,0.f,0.f};
  for (int e0 = w; e0 < nsel; e0 += 16) {
    const int e1 = e0 + 8;
    const bool h1 = (e1 < nsel);
    const f32x4* r0 = (const f32x4*)(supports + (size_t)s_selidx[e0] * DIM);
    f32x4 a0 = r0[lane], a1 = r0[lane + 64];
    f32x4 b0 = {0.f,0.f,0.f,0.f}, b1 = {0.f,0.f,0.f,0.f};
    if (h1) {
      const f32x4* r1 = (const f32x4*)(supports + (size_t)s_selidx[e1] * DIM);
      b0 = r1[lane]; b1 = r1[lane + 64];
    }
    float s0 = 0.f, s1 = 0.f;
#pragma unroll
    for (int j = 0; j < 4; ++j) {
      s0 = fmaf(a0[j], a0[j], s0); s0 = fmaf(a1[j], a1[j], s0);
      s1 = fmaf(b0[j], b0[j], s1); s1 = fmaf(b1[j], b1[j], s1);
    }
#pragma unroll
    for (int off = 32; off; off >>= 1) { s0 += __shfl_xor(s0, off); s1 += __shfl_xor(s1, off); }
    float c0 = 1.f / fmaxf(sqrtf(s0), 1e-12f);
    float c1 = 1.f / fmaxf(sqrtf(s1), 1e-12f);
#pragma unroll
    for (int j = 0; j < 4; ++j) { p0[j] = fmaf(a0[j], c0, p0[j]); p1[j] = fmaf(a1[j], c0, p1[j]); }
    if (h1) {
#pragma unroll
      for (int j = 0; j < 4; ++j) { p0[j] = fmaf(b0[j], c1, p0[j]); p1[j] = fmaf(b1[j], c1, p1[j]); }
    }
  }
  *(f32x4*)&s_part[w][lane * 4]       = p0;
  *(f32x4*)&s_part[w][256 + lane * 4] = p1;
  __syncthreads();
  float acc = 0.f;
#pragma unroll
  for (int ww = 0; ww < 8; ++ww) acc += s_part[ww][tid];
  float sq = acc * acc;
#pragma unroll
  for (int off = 32; off; off >>= 1) sq += __shfl_xor(sq, off);
  if (lane == 0) s_red[w] = sq;
  __syncthreads();
  float tot = 0.f;
#pragma unroll
  for (int ww = 0; ww < 8; ++ww) tot += s_red[ww];
  float sc = 1.f / fmaxf(sqrtf(tot), 1e-12f);
  {
    const int k = tid;
    const int kt = k >> 5, fq = (k >> 3) & 3, j = k & 7;
    const int ct = c >> 4, fr = c & 15;
    const size_t pos = (size_t)(kt * 24 + ct) * 512 + fq * 128 + fr * 8 + j;
    Wp[pos] = f2bf(acc * sc);
  }
}

// ---- Kernel B: out[M,345] = z[M,512] @ W ----
// R13 structure with the A-LDS layout replaced by a BALANCED fragment-linear
// layout: frag(mt,kt)=1KB, within-frag slot = (fq*16+fr) ^ (kt&15).
// Read: XOR bijection -> 64 distinct 16B slots/frag (b128 inherent minimum,
// no excess conflicts). Write: staging lane l covers k=8l -> slot'&7 spans
// all 8 bank windows evenly. B path / rotation / epilogue identical to R13.
__global__ __launch_bounds__(512, 4) void gemm_zw(
    const float* __restrict__ z, const short* __restrict__ Wp,
    float* __restrict__ out)
{
  __shared__ __align__(16) char lds[65536];      // A frags: 64 x 1KB
  const int tid  = threadIdx.x;
  const int lane = tid & 63;
  const int w    = tid >> 6;                     // wave 0..7 = 48-col group
  const int fr   = lane & 15, fq = lane >> 4;
  const int Mbase = blockIdx.x * 64;

  // ---- stage A: wave w stages rows {i*8+w}; frag-linear, balanced XOR ----
#pragma unroll
  for (int i = 0; i < 8; ++i) {
    const int row = i * 8 + w;
    const char* src = (const char*)(z + (size_t)(Mbase + row) * DIM);
    f32x4 u0 = *(const f32x4*)(src + lane * 32);        // k = 8*lane .. +3
    f32x4 u1 = *(const f32x4*)(src + lane * 32 + 16);   // k = 8*lane+4 .. +7
    s16x8 b;
#pragma unroll
    for (int j = 0; j < 4; ++j) { b[j] = f2bf(u0[j]); b[4 + j] = f2bf(u1[j]); }
    const int t  = lane >> 2, sfq = lane & 3;           // k = 32t + 8*sfq
    const int mt = row >> 4,  fr16 = row & 15;
    const unsigned slot = (unsigned)((sfq * 16 + fr16) ^ (t & 15));
    *(s16x8*)(lds + (size_t)(mt * 16 + t) * 1024 + slot * 16) = b;
  }
  __syncthreads();                               // only pre-epilogue barrier

  // B pointers: frag(kt, ct = w*3+nt) at (kt*24+ct)*1024 + lane*16
  const char* pb = (const char*)Wp + (size_t)w * 3 * 1024 + (size_t)lane * 16;

  f32x4 acc[4][3];
#pragma unroll
  for (int mt = 0; mt < 4; ++mt)
#pragma unroll
    for (int nt = 0; nt < 3; ++nt) acc[mt][nt] = f32x4{0.f, 0.f, 0.f, 0.f};

  s16x8 Bbuf[4][3];                              // distance-3 rotating prefetch
#pragma unroll
  for (int s = 0; s < 3; ++s)
#pragma unroll
    for (int nt = 0; nt < 3; ++nt)
      Bbuf[s][nt] = *(const s16x8*)(pb + (size_t)s * 24576 + nt * 1024);

#pragma unroll
  for (int t = 0; t < 16; ++t) {
    if (t + 3 < 16) {                            // prefetch t+3 (static slot)
#pragma unroll
      for (int nt = 0; nt < 3; ++nt)
        Bbuf[(t + 3) & 3][nt] = *(const s16x8*)(pb + (size_t)(t + 3) * 24576 + nt * 1024);
    }
    const unsigned rslot = (unsigned)(((fq * 16 + fr) ^ (t & 15)) * 16);
    s16x8 af[4];
#pragma unroll
    for (int mt = 0; mt < 4; ++mt)
      af[mt] = *(const s16x8*)(lds + (size_t)(mt * 16 + t) * 1024 + rslot);
    __builtin_amdgcn_s_setprio(1);
#pragma unroll
    for (int nt = 0; nt < 3; ++nt)
#pragma unroll
      for (int mt = 0; mt < 4; ++mt)
        acc[mt][nt] = __builtin_amdgcn_mfma_f32_16x16x32_bf16(Bbuf[t & 3][nt], af[mt], acc[mt][nt], 0, 0, 0);
    __builtin_amdgcn_s_setprio(0);
  }

  // ---- epilogue: two 32-row halves through LDS C-blob; NT stores ----
#pragma unroll
  for (int h = 0; h < 2; ++h) {
    __syncthreads();                   // h=0: A reads done; h=1: copy done
#pragma unroll
    for (int ml = 0; ml < 2; ++ml) {
      const int mt = h * 2 + ml;
      const int rl = ml * 16 + fr;     // local row 0..31
#pragma unroll
      for (int nt = 0; nt < 3; ++nt) {
        const int colb = w * 48 + nt * 16 + fq * 4;
#pragma unroll
        for (int j = 0; j < 4; ++j) {
          const int col = colb + j;
          if (col < NCLS)
            *(float*)(lds + (((size_t)rl * NCLS + col) << 2)) = acc[mt][nt][j];
        }
      }
    }
    __syncthreads();
    // flat coalesced nontemporal copy: 32*345*4 = 44160 B = 2760 x 16B
    char* dst = (char*)(out + (size_t)(Mbase + h * 32) * NCLS);
    for (int c = tid; c < 2760; c += 512) {
      f32x4 v = *(const f32x4*)(lds + c * 16);
      __builtin_nontemporal_store(v, (f32x4*)(dst + c * 16));
    }
  }
}

extern "C" void kernel_launch(void* const* d_in, const int* in_sizes, int n_in,
                              void* d_out, int out_size, void* d_ws, size_t ws_size,
                              hipStream_t stream) {
  const float* z        = (const float*)d_in[0];
  const float* supports = (const float*)d_in[1];
  const float* ent      = (const float*)d_in[2];
  const int*   y_hat    = (const int*)d_in[3];
  const int*   fK       = (const int*)d_in[4];
  float* out = (float*)d_out;
  short* Wp  = (short*)d_ws;           // fragment-packed W, 384 KB
  const int N = in_sizes[2];
  const int M = in_sizes[0] / DIM;

  const size_t offC = (size_t)CPAD * DIM * 2;          // 393216
  const size_t offB = offC + 2048;
  int* cnt    = (int*)((char*)d_ws + offC);
  u64* bucket = (u64*)((char*)d_ws + offB);
  hipMemsetAsync(cnt, 0, CPAD * sizeof(int), stream);
  scan_classes<<<dim3((N + 255) / 256), dim3(256), 0, stream>>>(ent, y_hat, bucket, cnt, N);
  select_accum<<<dim3(CPAD), dim3(512), 0, stream>>>(supports, bucket, cnt, fK, Wp);
  gemm_zw<<<dim3(M / 64), dim3(512), 0, stream>>>(z, Wp, out);
}